// Round 2
// baseline (130.303 us; speedup 1.0000x reference)
//
#include <hip/hip_runtime.h>
#include <cmath>

#define TT 1024
#define BB 8
#define IND 512
#define NCH 32
#define CHL 32          // TT / NCH
#define EPSV 1e-8
#define OUTHALF ((size_t)TT * BB * 4096)

// ---------------- K1: projections v,k,alpha (f32 GEMM, 8 rows/thread) ----------
__global__ __launch_bounds__(256)
void k1_proj(const float* __restrict__ x,
             const float* __restrict__ Wv, const float* __restrict__ bv,
             const float* __restrict__ Wk, const float* __restrict__ bk,
             const float* __restrict__ Wa, const float* __restrict__ ba,
             float* __restrict__ vOut, float* __restrict__ kOut,
             double* __restrict__ aOut)
{
    __shared__ float sWt[64][192];   // 48 KB transposed weight chunk (3 mats)
    __shared__ float sXt[64][32];    // 8 KB  transposed x chunk (32 rows)
    const int tid = threadIdx.x;
    const int rowbase = blockIdx.x * 32;          // 256 blocks * 32 rows
    const int c0 = tid & 63;                      // output col
    const int r0 = (tid >> 6) << 3;               // 8 rows per thread
    double av[8] = {}, ak[8] = {}, aa[8] = {};

    for (int ko = 0; ko < IND; ko += 64) {
        __syncthreads();
        if (tid < 192) {
            const float* src = (tid < 64  ? Wv + (size_t)tid * IND
                              : tid < 128 ? Wk + (size_t)(tid - 64) * IND
                              :             Wa + (size_t)(tid - 128) * IND) + ko;
            #pragma unroll
            for (int q = 0; q < 64; q += 4) {
                float4 w4 = *(const float4*)(src + q);
                sWt[q+0][tid] = w4.x; sWt[q+1][tid] = w4.y;
                sWt[q+2][tid] = w4.z; sWt[q+3][tid] = w4.w;
            }
        }
        {
            const int r  = tid & 31;
            const int kq = (tid >> 5) << 3;       // 0,8,...,56
            const float* xs = x + (size_t)(rowbase + r) * IND + ko + kq;
            float4 xa = *(const float4*)xs;
            float4 xb = *(const float4*)(xs + 4);
            sXt[kq+0][r] = xa.x; sXt[kq+1][r] = xa.y; sXt[kq+2][r] = xa.z; sXt[kq+3][r] = xa.w;
            sXt[kq+4][r] = xb.x; sXt[kq+5][r] = xb.y; sXt[kq+6][r] = xb.z; sXt[kq+7][r] = xb.w;
        }
        __syncthreads();

        float fv[8] = {}, fk[8] = {}, fa[8] = {};
        #pragma unroll
        for (int q = 0; q < 64; ++q) {
            float4 xa = *(const float4*)&sXt[q][r0];      // wave-uniform broadcast
            float4 xb = *(const float4*)&sXt[q][r0 + 4];
            float xr[8] = {xa.x, xa.y, xa.z, xa.w, xb.x, xb.y, xb.z, xb.w};
            float w0 = sWt[q][c0], w1 = sWt[q][c0 + 64], w2 = sWt[q][c0 + 128];
            #pragma unroll
            for (int j = 0; j < 8; ++j) {
                fv[j] = fmaf(xr[j], w0, fv[j]);
                fk[j] = fmaf(xr[j], w1, fk[j]);
                fa[j] = fmaf(xr[j], w2, fa[j]);
            }
        }
        #pragma unroll
        for (int j = 0; j < 8; ++j) { av[j] += fv[j]; ak[j] += fk[j]; aa[j] += fa[j]; }
    }

    #pragma unroll
    for (int j = 0; j < 8; ++j) {
        size_t r = (size_t)rowbase + r0 + j;
        vOut[r * 64 + c0] = (float)(av[j] + (double)bv[c0]);
        kOut[r * 64 + c0] = (float)(ak[j] + (double)bk[c0]);
        double z = aa[j] + (double)ba[c0];
        aOut[r * 64 + c0] = 1.0 / (1.0 + exp(-z));
    }
}

// ---------------- K2a: per-chunk alpha products --------------------------------
__global__ __launch_bounds__(256)
void k2a_chunkprod(const double* __restrict__ alpha, double* __restrict__ cpA)
{
    int gt = blockIdx.x * 256 + threadIdx.x;      // 16384 = 32 chunks * 512 chains
    int ch = gt >> 9, chain = gt & 511;
    double p = 1.0;
    int base = (ch * CHL) * 512 + chain;
    for (int i = 0; i < CHL; ++i) p *= alpha[base + i * 512];
    cpA[gt] = p;
}

// ---------------- KP: P[t,b,n] and kd[t,b,n] = k/(P+eps), prefix inline --------
__global__ __launch_bounds__(256)
void kP_scan(const float* __restrict__ kIn, const double* __restrict__ alpha,
             const double* __restrict__ cpA,
             double* __restrict__ Parr, double* __restrict__ kdArr)
{
    int gt = blockIdx.x * 256 + threadIdx.x;      // 16384
    int ch = gt >> 9, chain = gt & 511;           // ch uniform per block (2 blocks/ch)
    double P = 1.0;
    for (int c = 0; c < ch; ++c) P *= cpA[c * 512 + chain];
    int base = (ch * CHL) * 512 + chain;
    for (int i = 0; i < CHL; ++i) {
        int idx = base + i * 512;
        P *= alpha[idx];
        Parr[idx] = P;
        kdArr[idx] = (double)kIn[idx] / (P + EPSV);
    }
}

// ---------------- K3: per-chunk partial C sums ---------------------------------
__global__ __launch_bounds__(256)
void k3_csum(const float* __restrict__ vIn, const double* __restrict__ kdArr,
             double* __restrict__ Csum)
{
    __shared__ double sV[CHL * 64];               // 16 KB
    const int tid = threadIdx.x;
    const int ch = blockIdx.x >> 3;
    const int b  = blockIdx.x & 7;
    #pragma unroll
    for (int q = 0; q < 8; ++q) {
        int idx = q * 256 + tid;
        int ti = idx >> 6, d = idx & 63;
        sV[idx] = (double)vIn[(((ch * CHL + ti) * BB) + b) * 64 + d];
    }
    __syncthreads();
    const int n = tid & 63;
    const int w = tid >> 6;
    double C[16];
    #pragma unroll
    for (int j = 0; j < 16; ++j) C[j] = 0.0;
    for (int i = 0; i < CHL; ++i) {
        double kd = kdArr[((ch * CHL + i) * BB + b) * 64 + n];
        const double* vrow = &sV[i * 64 + w * 16];
        #pragma unroll
        for (int j = 0; j < 16; ++j) C[j] = fma(vrow[j], kd, C[j]);
    }
    size_t cb = ((size_t)ch * 8 + b) * 4096 + (size_t)w * 1024 + n;
    #pragma unroll
    for (int j = 0; j < 16; ++j) Csum[cb + j * 64] = C[j];
}

// ---------------- K3b: exclusive prefix sum of chunk partials ------------------
__global__ __launch_bounds__(256)
void k3b_prefix(double* __restrict__ Csum)
{
    int s = blockIdx.x * 256 + threadIdx.x;       // 32768 chains
    int b = s >> 12, rest = s & 4095;
    double run = 0.0;
    for (int ch = 0; ch < NCH; ++ch) {
        size_t idx = ((size_t)ch * 8 + b) * 4096 + rest;
        double t = Csum[idx];
        Csum[idx] = run;
        run += t;
    }
}

// ---------------- K4: main scan, writes spk + mem ------------------------------
__global__ __launch_bounds__(256)
void k4_scan(const float* __restrict__ vIn, const double* __restrict__ kdArr,
             const double* __restrict__ Parr, const double* __restrict__ Csum,
             float* __restrict__ outp)
{
    __shared__ double sV[CHL * 64];
    const int tid = threadIdx.x;
    const int ch = blockIdx.x >> 3;
    const int b  = blockIdx.x & 7;
    #pragma unroll
    for (int q = 0; q < 8; ++q) {
        int idx = q * 256 + tid;
        int ti = idx >> 6, d = idx & 63;
        sV[idx] = (double)vIn[(((ch * CHL + ti) * BB) + b) * 64 + d];
    }
    __syncthreads();
    const int n = tid & 63;
    const int w = tid >> 6;
    size_t cb = ((size_t)ch * 8 + b) * 4096 + (size_t)w * 1024 + n;
    double C[16];
    #pragma unroll
    for (int j = 0; j < 16; ++j) C[j] = Csum[cb + j * 64];

    float* spk = outp;
    float* mem = outp + OUTHALF;
    for (int i = 0; i < CHL; ++i) {
        int t = ch * CHL + i;
        int base = (t * BB + b) * 64 + n;
        double kd = kdArr[base];
        double P  = Parr[base];
        const double* vrow = &sV[i * 64 + w * 16];
        size_t ob = ((size_t)t * BB + b) * 4096 + (size_t)w * 1024 + n;
        #pragma unroll
        for (int j = 0; j < 16; ++j) {
            C[j] = fma(vrow[j], kd, C[j]);
            double S = P * C[j];
            mem[ob + j * 64] = (float)S;
            spk[ob + j * 64] = (S > 1.0) ? 1.0f : 0.0f;
        }
    }
}

// ---------------- launch -------------------------------------------------------
extern "C" void kernel_launch(void* const* d_in, const int* in_sizes, int n_in,
                              void* d_out, int out_size, void* d_ws, size_t ws_size,
                              hipStream_t stream)
{
    const float* x  = (const float*)d_in[0];
    const float* Wv = (const float*)d_in[1];
    const float* bv = (const float*)d_in[2];
    const float* Wk = (const float*)d_in[3];
    const float* bk = (const float*)d_in[4];
    const float* Wa = (const float*)d_in[5];
    const float* ba = (const float*)d_in[6];
    float* out = (float*)d_out;

    char* ws = (char*)d_ws;
    float*  v     = (float*)(ws);                                   // 2 MB
    float*  kk    = (float*)(ws + ( 2u << 20));                     // 2 MB
    double* alpha = (double*)(ws + ( 4u << 20));                    // 4 MB
    double* cpA   = (double*)(ws + ( 8u << 20));                    // 128 KB
    double* Parr  = (double*)(ws + ( 9u << 20));                    // 4 MB
    double* kdArr = (double*)(ws + (13u << 20));                    // 4 MB
    double* Csum  = (double*)(ws + (17u << 20));                    // 8 MB

    hipLaunchKernelGGL(k1_proj,       dim3(256), dim3(256), 0, stream,
                       x, Wv, bv, Wk, bk, Wa, ba, v, kk, alpha);
    hipLaunchKernelGGL(k2a_chunkprod, dim3(64),  dim3(256), 0, stream, alpha, cpA);
    hipLaunchKernelGGL(kP_scan,       dim3(64),  dim3(256), 0, stream,
                       kk, alpha, cpA, Parr, kdArr);
    hipLaunchKernelGGL(k3_csum,       dim3(256), dim3(256), 0, stream,
                       v, kdArr, Csum);
    hipLaunchKernelGGL(k3b_prefix,    dim3(128), dim3(256), 0, stream, Csum);
    hipLaunchKernelGGL(k4_scan,       dim3(256), dim3(256), 0, stream,
                       v, kdArr, Parr, Csum, out);
}